// Round 9
// baseline (161.871 us; speedup 1.0000x reference)
//
#include <hip/hip_runtime.h>
#include <math.h>

#define BATCH 4
#define CH    256   // feature channels == depth of sampled volume
#define HH    128
#define WW    128
#define PC    256   // para channels
#define PI_F  3.14159f
#define PLANE (HH * WW)   // 16384 floats

// Padded LDS plane: rows -1..129 (index y+1 in [0,130]), cols -1..132.
// Stride 134 words: 134 mod 32 = 6 -> linear lane-walks spread banks.
// Border + padding cells hold 0.0f: OOB sampling reads stored zeros =>
// padding_mode='zeros' with NO mask VALU in the gather.
#define PSTRIDE 134
#define PROWS   131
#define BUFSZ   (PROWS * PSTRIDE)   // 17554 words = 70216 B
#define NBORDER 1170                // BUFSZ - 128*128 interior words

// Light barrier: drains LDS ops only (lgkmcnt), NOT vmcnt.
__device__ __forceinline__ void barrier_lds() {
    asm volatile("s_waitcnt lgkmcnt(0)\n\ts_barrier" ::: "memory");
}

struct Stage { float4 a[4]; float4 b[4]; };

__device__ __forceinline__ Stage stage_load(const float* __restrict__ pl0,
                                            const float* __restrict__ pl1, int t) {
    Stage s;
#pragma unroll
    for (int j = 0; j < 4; ++j) {
        const int f = 4 * (t + 1024 * j);
        s.a[j] = *(const float4*)(pl0 + f);
        s.b[j] = *(const float4*)(pl1 + f);
    }
    return s;
}

// z-combine + scatter into padded layout (interior cells only; border cells
// remain zero). 4 consecutive floats -> compiler merges to ds_write2_b32.
__device__ __forceinline__ void stage_store_pad(float* __restrict__ buf, const Stage& s,
                                                float wz0, float wz1, int t) {
#pragma unroll
    for (int j = 0; j < 4; ++j) {
        const int f = 4 * (t + 1024 * j);
        const int y = f >> 7, x = f & (WW - 1);
        float* p = &buf[(y + 1) * PSTRIDE + (x + 1)];
        p[0] = fmaf(wz0, s.a[j].x, wz1 * s.b[j].x);
        p[1] = fmaf(wz0, s.a[j].y, wz1 * s.b[j].y);
        p[2] = fmaf(wz0, s.a[j].z, wz1 * s.b[j].z);
        p[3] = fmaf(wz0, s.a[j].w, wz1 * s.b[j].w);
    }
}

// ---------------------------------------------------------------------------
// Params kernel: 4 blocks (one per batch) x 1024 threads. Computes the whole
// per-(batch,channel) affine parameter chain ONCE and writes 1024 float4 to
// the workspace. Removes GEMV + head-dots + transcendentals + 4 barriers from
// each of the 1024 main-kernel blocks (262 MB of re-read W1 L2 traffic gone).
// ---------------------------------------------------------------------------
__global__ __launch_bounds__(1024)
void adaat_params_kernel(const float* __restrict__ pc,
                         const float* __restrict__ W1, const float* __restrict__ b1,
                         const float* __restrict__ Ws, const float* __restrict__ bs,
                         const float* __restrict__ Wr, const float* __restrict__ br,
                         const float* __restrict__ Wt, const float* __restrict__ bt,
                         float4* __restrict__ par) {
    __shared__ float red[1024];
    __shared__ float p_sh[PC];
    __shared__ float hd[4][PC];

    const int t = threadIdx.x;
    const int b = blockIdx.x;

    // ---- p = relu(pc @ W1 + b1), 4-way k-split (same rounding as before) --
    {
        const int jj = t & 255, kk = t >> 8;
        const float* pcb = pc + b * PC + kk * 64;
        const float* w   = W1 + (kk * 64) * PC + jj;
        float acc = 0.0f;
#pragma unroll 8
        for (int i = 0; i < 64; ++i)
            acc = fmaf(pcb[i], w[i * PC], acc);
        red[t] = acc;
    }
    __syncthreads();
    if (t < 256)
        p_sh[t] = fmaxf(red[t] + red[256 + t] + red[512 + t] + red[768 + t] + b1[t], 0.0f);
    __syncthreads();

    // ---- head dots: thread = (channel c, head h), coalesced across c ------
    {
        const int c = t & 255, h = t >> 8;
        const float* wp; int stride;
        if      (h == 0) { wp = Ws + c;                stride = PC;     }
        else if (h == 1) { wp = Wr + c;                stride = PC;     }
        else             { wp = Wt + 2 * c + (h == 3); stride = 2 * PC; }
        float dot = 0.0f;
#pragma unroll 8
        for (int k = 0; k < PC; ++k)
            dot = fmaf(p_sh[k], wp[(size_t)k * stride], dot);
        hd[h][c] = dot;
    }
    __syncthreads();

    // ---- transcendentals -> fused padded-pixel-space constants ------------
    if (t < 256) {
        const int c = t;
        const float s2  = 2.0f / (1.0f + expf(-(hd[0][c] + bs[c])));
        const float ang = tanhf(hd[1][c] + br[c]) * PI_F;
        float sa, ca;
        sincosf(ang, &sa, &ca);
        const float A  = s2 * ca, B = s2 * sa;
        const float Tx = tanhf(hd[2][c] + bt[2 * c]);
        const float Ty = tanhf(hd[3][c] + bt[2 * c + 1]);
        par[b * 256 + c] = make_float4(A * (128.0f / 127.0f),
                                       B * (128.0f / 127.0f),
                                       64.0f * (Tx - A + B) + 64.5f,   // +1 border bias
                                       64.0f * (Ty - A - B) + 64.5f);
    }
}

// ---------------------------------------------------------------------------
// Main kernel: 1024 blocks x 1024 threads, one plane per block, single padded
// LDS buffer (70.2 KiB) => 2 blocks/CU, 32 waves/CU. With params precomputed
// the block is a straight-line pipe: plane load -> border zero -> scatter ->
// ONE barrier -> gather -> coalesced store.
// ---------------------------------------------------------------------------
__global__ __launch_bounds__(1024, 8)
void adaat_fused_kernel(const float* __restrict__ fm,
                        const float4* __restrict__ par,
                        float* __restrict__ out) {
    __shared__ float lds[BUFSZ];   // 70.2 KiB single padded plane

    const int t = threadIdx.x;

    // XCD-chunked swizzle (grid 1024 = 8 XCDs x 128, bijective): each XCD
    // owns a contiguous channel range -> adjacent channels share a source
    // plane in the same per-XCD L2 (FETCH 65->37 MB measured in R1).
    const int bid = blockIdx.x;
    const int lc  = ((bid & 7) << 7) | (bid >> 3);   // logical (batch,channel)
    const int b   = lc >> 8;
    const int c   = lc & (CH - 1);

    // block-uniform staging constants (scalarized)
    const float* base = fm + (size_t)b * (CH * PLANE);
    const float  iz = (256.0f / 255.0f) * (float)c - 0.5f;
    const float  zf = floorf(iz);
    const float  fz = iz - zf;
    const int    z0 = (int)zf;
    const float  w0 = (z0 >= 0)     ? (1.0f - fz) : 0.0f;
    const float  w1 = (z0 + 1 < CH) ? fz          : 0.0f;
    const float* pl0 = base + (size_t)max(z0, 0)          * PLANE;
    const float* pl1 = base + (size_t)min(z0 + 1, CH - 1) * PLANE;

    // ---- 1) plane staging loads issued first, stay in flight ----
    Stage s = stage_load(pl0, pl1, t);

    // ---- 2) params: block-uniform scalar load (latency hidden) ----
    const float4 P = par[lc];

    // ---- 3) zero ONLY the border cells (1170 words; interior is fully
    //         overwritten by stage_store_pad). Rows 0,129,130 full; rows
    //         1..128 cols {0,129..133}. ----
#pragma unroll
    for (int i = t; i < NBORDER; i += 1024) {
        int row, col;
        if (i < 402) {
            row = i / 134;
            if (row == 1) row = 129; else if (row == 2) row = 130;
            col = i % 134;
        } else {
            const int j = i - 402;
            row = 1 + j / 6;
            const int cs = j % 6;
            col = (cs == 0) ? 0 : 128 + cs;
        }
        lds[row * PSTRIDE + col] = 0.0f;
    }

    // ---- 4) z-combine + scatter (waits only its own vmcnt) ----
    stage_store_pad(lds, s, w0, w1, t);

    barrier_lds();   // all LDS writes visible; the ONLY barrier

    // ---- 5) gather: wave wv owns rows [8wv, 8wv+8), lane = column ----
    // 64 lanes store 64 consecutive dwords (256 B / instr). Clamp coord into
    // [0, 129.99]: far-OOB pixels land entirely on zero cells; edge pixels
    // get the exact zero-padded bilinear weights.
    {
        const int    wv = t >> 6, l = t & 63;
        const float  cA = P.x, cB = P.y;
        float* outp = out + (size_t)lc * PLANE;
        const float xf0 = (float)l;
        float rowf = (float)(wv * 8);
#pragma unroll 2
        for (int r = 0; r < 8; ++r) {
            const float bx = fmaf(-cB, rowf, P.z);   // per-row partials
            const float by = fmaf( cA, rowf, P.w);
            float* orow = outp + (wv * 8 + r) * WW;
#pragma unroll
            for (int h = 0; h < 2; ++h) {
                const float xf  = xf0 + 64.0f * h;
                const float ix  = fmaf(cA, xf, bx);
                const float iy  = fmaf(cB, xf, by);
                const float xc  = fminf(fmaxf(ix, 0.0f), 129.99f);
                const float yc  = fminf(fmaxf(iy, 0.0f), 129.99f);
                const float x0f = floorf(xc), y0f = floorf(yc);
                const float fx  = xc - x0f,   fy  = yc - y0f;
                const int   a   = (int)y0f * PSTRIDE + (int)x0f;
                const float v00 = lds[a],           v01 = lds[a + 1];           // ds_read2
                const float v10 = lds[a + PSTRIDE], v11 = lds[a + PSTRIDE + 1]; // ds_read2
                const float h0  = fmaf(fx, v01 - v00, v00);
                const float h1  = fmaf(fx, v11 - v10, v10);
                orow[h * 64 + l] = fmaf(fy, h1 - h0, h0);
            }
            rowf += 1.0f;
        }
    }
}

// ---------------------------------------------------------------------------
extern "C" void kernel_launch(void* const* d_in, const int* in_sizes, int n_in,
                              void* d_out, int out_size, void* d_ws, size_t ws_size,
                              hipStream_t stream) {
    const float* feature_map = (const float*)d_in[0];  // [4,256,128,128]
    const float* para_code   = (const float*)d_in[1];  // [4,256]
    const float* W1 = (const float*)d_in[2];
    const float* b1 = (const float*)d_in[3];
    const float* Ws = (const float*)d_in[4];
    const float* bs = (const float*)d_in[5];
    const float* Wr = (const float*)d_in[6];
    const float* br = (const float*)d_in[7];
    const float* Wt = (const float*)d_in[8];
    const float* bt = (const float*)d_in[9];

    float4* par = (float4*)d_ws;   // 1024 * 16 B = 16 KiB

    adaat_params_kernel<<<BATCH, 1024, 0, stream>>>(
        para_code, W1, b1, Ws, bs, Wr, br, Wt, bt, par);

    adaat_fused_kernel<<<BATCH * CH, 1024, 0, stream>>>(
        feature_map, par, (float*)d_out);
}

// Round 12
// 143.748 us; speedup vs baseline: 1.1261x; 1.1261x over previous
//
#include <hip/hip_runtime.h>
#include <math.h>

#define BATCH 4
#define CH    256   // feature channels == depth of sampled volume
#define HH    128
#define WW    128
#define PC    256   // para channels
#define PI_F  3.14159f
#define PLANE (HH * WW)   // 16384 floats

// Padded LDS plane: rows -1..129 (index y+1 in [0,130]), cols -1..132.
// Stride 134 words: 134 mod 32 = 6 -> linear lane-walks spread banks.
// Border + padding cells hold 0.0f: OOB sampling reads stored zeros =>
// padding_mode='zeros' with NO mask VALU in the gather.
#define PSTRIDE 134
#define PROWS   131
#define BUFSZ   (PROWS * PSTRIDE)   // 17554 words = 70216 B
#define NBORDER 1170                // BUFSZ - 128*128 interior words

// Workspace layout (floats): [0,1024) p; [1024,2048) hd_s; [2048,3072) hd_r;
// [3072,5120) ht (b*512 + col). Total 20 KiB.
#define WS_P    0
#define WS_S    1024
#define WS_R    2048
#define WS_T    3072

// Light barrier: drains LDS ops only (lgkmcnt), NOT vmcnt.
__device__ __forceinline__ void barrier_lds() {
    asm volatile("s_waitcnt lgkmcnt(0)\n\ts_barrier" ::: "memory");
}

struct Stage { float4 a[4]; float4 b[4]; };

__device__ __forceinline__ Stage stage_load(const float* __restrict__ pl0,
                                            const float* __restrict__ pl1, int t) {
    Stage s;
#pragma unroll
    for (int j = 0; j < 4; ++j) {
        const int f = 4 * (t + 1024 * j);
        s.a[j] = *(const float4*)(pl0 + f);
        s.b[j] = *(const float4*)(pl1 + f);
    }
    return s;
}

// z-combine + scatter into padded layout (interior cells only; border cells
// remain zero). 4 consecutive floats -> compiler merges to ds_write2_b32.
__device__ __forceinline__ void stage_store_pad(float* __restrict__ buf, const Stage& s,
                                                float wz0, float wz1, int t) {
#pragma unroll
    for (int j = 0; j < 4; ++j) {
        const int f = 4 * (t + 1024 * j);
        const int y = f >> 7, x = f & (WW - 1);
        float* p = &buf[(y + 1) * PSTRIDE + (x + 1)];
        p[0] = fmaf(wz0, s.a[j].x, wz1 * s.b[j].x);
        p[1] = fmaf(wz0, s.a[j].y, wz1 * s.b[j].y);
        p[2] = fmaf(wz0, s.a[j].z, wz1 * s.b[j].z);
        p[3] = fmaf(wz0, s.a[j].w, wz1 * s.b[j].w);
    }
}

// ---------------------------------------------------------------------------
// P1: p = relu(pc @ W1 + b1). 4 blocks x 1024 threads, 4-way k-split (the
// proven R1 GEMV structure, same rounding). Writes p[4][256] to workspace.
// ---------------------------------------------------------------------------
__global__ __launch_bounds__(1024)
void adaat_p1_kernel(const float* __restrict__ pc,
                     const float* __restrict__ W1, const float* __restrict__ b1,
                     float* __restrict__ ws) {
    __shared__ float red[1024];
    const int t = threadIdx.x;
    const int b = blockIdx.x;
    {
        const int jj = t & 255, kk = t >> 8;
        const float* pcb = pc + b * PC + kk * 64;
        const float* w   = W1 + (kk * 64) * PC + jj;
        float acc = 0.0f;
#pragma unroll 8
        for (int i = 0; i < 64; ++i)
            acc = fmaf(pcb[i], w[i * PC], acc);
        red[t] = acc;
    }
    __syncthreads();
    if (t < 256)
        ws[WS_P + b * 256 + t] =
            fmaxf(red[t] + red[256 + t] + red[512 + t] + red[768 + t] + b1[t], 0.0f);
}

// ---------------------------------------------------------------------------
// P2: head dots, k-split AND head-parallel. 16 blocks x 1024 threads:
// block = (batch b, group g). g=0 -> Ws cols 0..255; g=1 -> Wr cols 0..255;
// g=2 -> Wt cols 0..255; g=3 -> Wt cols 256..511. thread = (o = t&255,
// kk = t>>8): 64 MACs each (vs 256 serial in R9's 4-block version), LDS
// reduce. The 4 groups run on DIFFERENT CUs concurrently. Raw dots (no
// bias) to workspace; main kernel applies biases + transcendentals.
// ---------------------------------------------------------------------------
__global__ __launch_bounds__(1024)
void adaat_p2_kernel(const float* __restrict__ Ws,
                     const float* __restrict__ Wr,
                     const float* __restrict__ Wt,
                     float* __restrict__ ws) {
    __shared__ float red[1024];
    __shared__ float p_sh[PC];
    const int t = threadIdx.x;
    const int b = blockIdx.x >> 2;
    const int g = blockIdx.x & 3;

    if (t < 256) p_sh[t] = ws[WS_P + b * 256 + t];
    __syncthreads();

    const int o = t & 255, kk = t >> 8;
    const float* wp; int stride; int dst;
    if      (g == 0) { wp = Ws + o;       stride = PC;     dst = WS_S + b * 256 + o;       }
    else if (g == 1) { wp = Wr + o;       stride = PC;     dst = WS_R + b * 256 + o;       }
    else if (g == 2) { wp = Wt + o;       stride = 2 * PC; dst = WS_T + b * 512 + o;       }
    else             { wp = Wt + 256 + o; stride = 2 * PC; dst = WS_T + b * 512 + 256 + o; }

    float acc = 0.0f;
    const float* pk = p_sh + kk * 64;
    const float* wk = wp + (size_t)(kk * 64) * stride;
#pragma unroll 8
    for (int i = 0; i < 64; ++i)
        acc = fmaf(pk[i], wk[(size_t)i * stride], acc);
    red[t] = acc;
    __syncthreads();
    if (t < 256)
        ws[dst] = red[t] + red[256 + t] + red[512 + t] + red[768 + t];
}

// ---------------------------------------------------------------------------
// Main kernel: 1024 blocks x 1024 threads, one plane per block, single padded
// LDS buffer (70.2 KiB) => 2 blocks/CU, 32 waves/CU. Straight-line pipe:
// plane load -> (t0: biases+transcendentals, hidden under load burst) ->
// border zero -> scatter -> ONE barrier -> gather -> coalesced store.
// ---------------------------------------------------------------------------
__global__ __launch_bounds__(1024, 8)
void adaat_fused_kernel(const float* __restrict__ fm,
                        const float* __restrict__ ws,
                        const float* __restrict__ bs,
                        const float* __restrict__ br,
                        const float* __restrict__ bt,
                        float* __restrict__ out) {
    __shared__ float  lds[BUFSZ];   // 70.2 KiB single padded plane
    __shared__ float4 sh_par;

    const int t = threadIdx.x;

    // XCD-chunked swizzle (grid 1024 = 8 XCDs x 128, bijective): each XCD
    // owns a contiguous channel range -> adjacent channels share a source
    // plane in the same per-XCD L2 (FETCH 65->37 MB measured in R1).
    const int bid = blockIdx.x;
    const int lc  = ((bid & 7) << 7) | (bid >> 3);   // logical (batch,channel)
    const int b   = lc >> 8;
    const int c   = lc & (CH - 1);

    // block-uniform staging constants (scalarized)
    const float* base = fm + (size_t)b * (CH * PLANE);
    const float  iz = (256.0f / 255.0f) * (float)c - 0.5f;
    const float  zf = floorf(iz);
    const float  fz = iz - zf;
    const int    z0 = (int)zf;
    const float  w0 = (z0 >= 0)     ? (1.0f - fz) : 0.0f;
    const float  w1 = (z0 + 1 < CH) ? fz          : 0.0f;
    const float* pl0 = base + (size_t)max(z0, 0)          * PLANE;
    const float* pl1 = base + (size_t)min(z0 + 1, CH - 1) * PLANE;

    // ---- 1) plane staging loads issued first, stay in flight ----
    Stage s = stage_load(pl0, pl1, t);

    // ---- 2) t0: per-channel transcendentals (~1.5k cyc, hidden under the
    //         ~8 us load burst of the other 1023 threads) ----
    if (t == 0) {
        const float ds  = ws[WS_S + lc];
        const float dr  = ws[WS_R + lc];
        const float dt0 = ws[WS_T + b * 512 + 2 * c];
        const float dt1 = ws[WS_T + b * 512 + 2 * c + 1];
        const float s2  = 2.0f / (1.0f + expf(-(ds + bs[c])));
        const float ang = tanhf(dr + br[c]) * PI_F;
        float sa, ca;
        sincosf(ang, &sa, &ca);
        const float A  = s2 * ca, B = s2 * sa;
        const float Tx = tanhf(dt0 + bt[2 * c]);
        const float Ty = tanhf(dt1 + bt[2 * c + 1]);
        sh_par = make_float4(A * (128.0f / 127.0f),
                             B * (128.0f / 127.0f),
                             64.0f * (Tx - A + B) + 64.5f,   // +1 border bias
                             64.0f * (Ty - A - B) + 64.5f);
    }

    // ---- 3) zero ONLY the border cells (1170 words; interior is fully
    //         overwritten by stage_store_pad). Rows 0,129,130 full; rows
    //         1..128 cols {0,129..133}. ----
#pragma unroll
    for (int i = t; i < NBORDER; i += 1024) {
        int row, col;
        if (i < 402) {
            row = i / 134;
            if (row == 1) row = 129; else if (row == 2) row = 130;
            col = i % 134;
        } else {
            const int j = i - 402;
            row = 1 + j / 6;
            const int cs = j % 6;
            col = (cs == 0) ? 0 : 128 + cs;
        }
        lds[row * PSTRIDE + col] = 0.0f;
    }

    // ---- 4) z-combine + scatter (waits only its own vmcnt) ----
    stage_store_pad(lds, s, w0, w1, t);

    barrier_lds();   // all LDS writes (incl. sh_par) visible; the ONLY barrier

    // ---- 5) gather: wave wv owns rows [8wv, 8wv+8), lane = column ----
    // 64 lanes store 64 consecutive dwords (256 B / instr). Clamp coord into
    // [0, 129.99]: far-OOB pixels land entirely on zero cells; edge pixels
    // get the exact zero-padded bilinear weights.
    {
        const int    wv = t >> 6, l = t & 63;
        const float4 P  = sh_par;
        const float  cA = P.x, cB = P.y;
        float* outp = out + (size_t)lc * PLANE;
        const float xf0 = (float)l;
        float rowf = (float)(wv * 8);
#pragma unroll 2
        for (int r = 0; r < 8; ++r) {
            const float bx = fmaf(-cB, rowf, P.z);   // per-row partials
            const float by = fmaf( cA, rowf, P.w);
            float* orow = outp + (wv * 8 + r) * WW;
#pragma unroll
            for (int h = 0; h < 2; ++h) {
                const float xf  = xf0 + 64.0f * h;
                const float ix  = fmaf(cA, xf, bx);
                const float iy  = fmaf(cB, xf, by);
                const float xc  = fminf(fmaxf(ix, 0.0f), 129.99f);
                const float yc  = fminf(fmaxf(iy, 0.0f), 129.99f);
                const float x0f = floorf(xc), y0f = floorf(yc);
                const float fx  = xc - x0f,   fy  = yc - y0f;
                const int   a   = (int)y0f * PSTRIDE + (int)x0f;
                const float v00 = lds[a],           v01 = lds[a + 1];           // ds_read2
                const float v10 = lds[a + PSTRIDE], v11 = lds[a + PSTRIDE + 1]; // ds_read2
                const float h0  = fmaf(fx, v01 - v00, v00);
                const float h1  = fmaf(fx, v11 - v10, v10);
                orow[h * 64 + l] = fmaf(fy, h1 - h0, h0);
            }
            rowf += 1.0f;
        }
    }
}

// ---------------------------------------------------------------------------
extern "C" void kernel_launch(void* const* d_in, const int* in_sizes, int n_in,
                              void* d_out, int out_size, void* d_ws, size_t ws_size,
                              hipStream_t stream) {
    const float* feature_map = (const float*)d_in[0];  // [4,256,128,128]
    const float* para_code   = (const float*)d_in[1];  // [4,256]
    const float* W1 = (const float*)d_in[2];
    const float* b1 = (const float*)d_in[3];
    const float* Ws = (const float*)d_in[4];
    const float* bs = (const float*)d_in[5];
    const float* Wr = (const float*)d_in[6];
    const float* br = (const float*)d_in[7];
    const float* Wt = (const float*)d_in[8];
    const float* bt = (const float*)d_in[9];

    float* ws = (float*)d_ws;   // 5120 floats = 20 KiB

    adaat_p1_kernel<<<BATCH, 1024, 0, stream>>>(para_code, W1, b1, ws);
    adaat_p2_kernel<<<4 * BATCH, 1024, 0, stream>>>(Ws, Wr, Wt, ws);
    adaat_fused_kernel<<<BATCH * CH, 1024, 0, stream>>>(
        feature_map, ws, bs, br, bt, (float*)d_out);
}

// Round 15
// 143.210 us; speedup vs baseline: 1.1303x; 1.0038x over previous
//
#include <hip/hip_runtime.h>
#include <math.h>

#define BATCH 4
#define CH    256   // feature channels == depth of sampled volume
#define HH    128
#define WW    128
#define PC    256   // para channels
#define PI_F  3.14159f
#define PLANE (HH * WW)   // 16384 floats

// Padded LDS plane: rows -1..129 (index y+1 in [0,130]), cols -1..132.
// Stride 134 words (VERIFIED R12 geometry): 134 mod 32 = 6 -> linear
// lane-walks spread banks. Border + padding cells hold 0.0f: OOB sampling
// reads stored zeros => padding_mode='zeros' with NO mask VALU.
#define PSTRIDE 134
#define PROWS   131
#define BUFSZ   (PROWS * PSTRIDE)   // 17554 words = 70216 B
#define NBORDER 1170                // BUFSZ - 128*128 interior words

// Workspace layout (floats): [1024,2048) hd_s; [2048,3072) hd_r;
// [3072,5120) ht (b*512 + col). Total 20 KiB. (p stays in LDS now.)
#define WS_S    1024
#define WS_R    2048
#define WS_T    3072

// Light barrier: drains LDS ops only (lgkmcnt), NOT vmcnt.
__device__ __forceinline__ void barrier_lds() {
    asm volatile("s_waitcnt lgkmcnt(0)\n\ts_barrier" ::: "memory");
}

struct Stage { float4 a[4]; float4 b[4]; };

__device__ __forceinline__ Stage stage_load(const float* __restrict__ pl0,
                                            const float* __restrict__ pl1, int t) {
    Stage s;
#pragma unroll
    for (int j = 0; j < 4; ++j) {
        const int f = 4 * (t + 1024 * j);
        s.a[j] = *(const float4*)(pl0 + f);
        s.b[j] = *(const float4*)(pl1 + f);
    }
    return s;
}

// z-combine + scatter into padded layout (interior cells only; border cells
// remain zero). 4 consecutive floats -> compiler merges to ds_write2_b32.
__device__ __forceinline__ void stage_store_pad(float* __restrict__ buf, const Stage& s,
                                                float wz0, float wz1, int t) {
#pragma unroll
    for (int j = 0; j < 4; ++j) {
        const int f = 4 * (t + 1024 * j);
        const int y = f >> 7, x = f & (WW - 1);
        float* p = &buf[(y + 1) * PSTRIDE + (x + 1)];
        p[0] = fmaf(wz0, s.a[j].x, wz1 * s.b[j].x);
        p[1] = fmaf(wz0, s.a[j].y, wz1 * s.b[j].y);
        p[2] = fmaf(wz0, s.a[j].z, wz1 * s.b[j].z);
        p[3] = fmaf(wz0, s.a[j].w, wz1 * s.b[j].w);
    }
}

// ---------------------------------------------------------------------------
// Merged params kernel: 16 blocks x 1024 threads, block = (batch b, group g).
// Phase B weights (head-dot) do NOT depend on p, so all 64 are prefetched
// into registers FIRST (HBM latency hides under phase A). Phase A: each block
// redundantly computes its batch's full GEMV p = relu(pc@W1+b1) into LDS
// (identical k-split rounding as the verified P1). Phase B: head dots from
// registers + p_sh, LDS reduce, raw dots to workspace. One launch, no global
// round-trip for p: replaces the R12 P1+P2 pair (~11 us) at ~4-6 us.
// ---------------------------------------------------------------------------
__global__ __launch_bounds__(1024)
void adaat_params_kernel(const float* __restrict__ pc,
                         const float* __restrict__ W1, const float* __restrict__ b1,
                         const float* __restrict__ Ws,
                         const float* __restrict__ Wr,
                         const float* __restrict__ Wt,
                         float* __restrict__ ws) {
    __shared__ float red[1024];
    __shared__ float p_sh[PC];
    const int t = threadIdx.x;
    const int b = blockIdx.x >> 2;
    const int g = blockIdx.x & 3;
    const int o = t & 255, kk = t >> 8;

    // ---- phase-B weight prefetch (independent of p; issued first) ----
    const float* wp; int stride; int dst;
    if      (g == 0) { wp = Ws + o;       stride = PC;     dst = WS_S + b * 256 + o;       }
    else if (g == 1) { wp = Wr + o;       stride = PC;     dst = WS_R + b * 256 + o;       }
    else if (g == 2) { wp = Wt + o;       stride = 2 * PC; dst = WS_T + b * 512 + o;       }
    else             { wp = Wt + 256 + o; stride = 2 * PC; dst = WS_T + b * 512 + 256 + o; }
    float wb[64];
    {
        const float* wkB = wp + (size_t)(kk * 64) * stride;
#pragma unroll
        for (int i = 0; i < 64; ++i)
            wb[i] = wkB[(size_t)i * stride];
    }

    // ---- phase A: p = relu(pc @ W1 + b1), 4-way k-split (P1 rounding) ----
    {
        const float* pcb = pc + b * PC + kk * 64;
        const float* w   = W1 + (kk * 64) * PC + o;
        float acc = 0.0f;
#pragma unroll 8
        for (int i = 0; i < 64; ++i)
            acc = fmaf(pcb[i], w[i * PC], acc);
        red[t] = acc;
    }
    __syncthreads();
    if (t < 256)
        p_sh[t] = fmaxf(red[t] + red[256 + t] + red[512 + t] + red[768 + t] + b1[t], 0.0f);
    __syncthreads();

    // ---- phase B: head dots from prefetched registers (P2 rounding) ----
    {
        const float* pk = p_sh + kk * 64;
        float acc = 0.0f;
#pragma unroll
        for (int i = 0; i < 64; ++i)
            acc = fmaf(pk[i], wb[i], acc);
        red[t] = acc;
    }
    __syncthreads();
    if (t < 256)
        ws[dst] = red[t] + red[256 + t] + red[512 + t] + red[768 + t];
}

// ---------------------------------------------------------------------------
// Main kernel: byte-identical to the VERIFIED R12 version (PSTRIDE 134).
// 1024 blocks x 1024 threads, one plane per block, single padded LDS buffer
// (70.2 KiB) => 2 blocks/CU, 32 waves/CU. Straight-line pipe: plane load ->
// (t0: biases+transcendentals, hidden under load burst) -> border zero ->
// scatter -> ONE barrier -> gather -> coalesced store.
// ---------------------------------------------------------------------------
__global__ __launch_bounds__(1024, 8)
void adaat_fused_kernel(const float* __restrict__ fm,
                        const float* __restrict__ ws,
                        const float* __restrict__ bs,
                        const float* __restrict__ br,
                        const float* __restrict__ bt,
                        float* __restrict__ out) {
    __shared__ float  lds[BUFSZ];   // 70.2 KiB single padded plane
    __shared__ float4 sh_par;

    const int t = threadIdx.x;

    // XCD-chunked swizzle (grid 1024 = 8 XCDs x 128, bijective): each XCD
    // owns a contiguous channel range -> adjacent channels share a source
    // plane in the same per-XCD L2 (FETCH 65->37 MB measured in R1).
    const int bid = blockIdx.x;
    const int lc  = ((bid & 7) << 7) | (bid >> 3);   // logical (batch,channel)
    const int b   = lc >> 8;
    const int c   = lc & (CH - 1);

    // block-uniform staging constants (scalarized)
    const float* base = fm + (size_t)b * (CH * PLANE);
    const float  iz = (256.0f / 255.0f) * (float)c - 0.5f;
    const float  zf = floorf(iz);
    const float  fz = iz - zf;
    const int    z0 = (int)zf;
    const float  w0 = (z0 >= 0)     ? (1.0f - fz) : 0.0f;
    const float  w1 = (z0 + 1 < CH) ? fz          : 0.0f;
    const float* pl0 = base + (size_t)max(z0, 0)          * PLANE;
    const float* pl1 = base + (size_t)min(z0 + 1, CH - 1) * PLANE;

    // ---- 1) plane staging loads issued first, stay in flight ----
    Stage s = stage_load(pl0, pl1, t);

    // ---- 2) t0: per-channel transcendentals (~1.5k cyc, hidden under the
    //         ~8 us load burst of the other 1023 threads) ----
    if (t == 0) {
        const float ds  = ws[WS_S + lc];
        const float dr  = ws[WS_R + lc];
        const float dt0 = ws[WS_T + b * 512 + 2 * c];
        const float dt1 = ws[WS_T + b * 512 + 2 * c + 1];
        const float s2  = 2.0f / (1.0f + expf(-(ds + bs[c])));
        const float ang = tanhf(dr + br[c]) * PI_F;
        float sa, ca;
        sincosf(ang, &sa, &ca);
        const float A  = s2 * ca, B = s2 * sa;
        const float Tx = tanhf(dt0 + bt[2 * c]);
        const float Ty = tanhf(dt1 + bt[2 * c + 1]);
        sh_par = make_float4(A * (128.0f / 127.0f),
                             B * (128.0f / 127.0f),
                             64.0f * (Tx - A + B) + 64.5f,   // +1 border bias
                             64.0f * (Ty - A - B) + 64.5f);
    }

    // ---- 3) zero ONLY the border cells (1170 words; interior is fully
    //         overwritten by stage_store_pad). Rows 0,129,130 full; rows
    //         1..128 cols {0,129..133}. ----
#pragma unroll
    for (int i = t; i < NBORDER; i += 1024) {
        int row, col;
        if (i < 402) {
            row = i / 134;
            if (row == 1) row = 129; else if (row == 2) row = 130;
            col = i % 134;
        } else {
            const int j = i - 402;
            row = 1 + j / 6;
            const int cs = j % 6;
            col = (cs == 0) ? 0 : 128 + cs;
        }
        lds[row * PSTRIDE + col] = 0.0f;
    }

    // ---- 4) z-combine + scatter (waits only its own vmcnt) ----
    stage_store_pad(lds, s, w0, w1, t);

    barrier_lds();   // all LDS writes (incl. sh_par) visible; the ONLY barrier

    // ---- 5) gather: wave wv owns rows [8wv, 8wv+8), lane = column ----
    // 64 lanes store 64 consecutive dwords (256 B / instr). Clamp coord into
    // [0, 129.99]: far-OOB pixels land entirely on zero cells; edge pixels
    // get the exact zero-padded bilinear weights.
    {
        const int    wv = t >> 6, l = t & 63;
        const float4 P  = sh_par;
        const float  cA = P.x, cB = P.y;
        float* outp = out + (size_t)lc * PLANE;
        const float xf0 = (float)l;
        float rowf = (float)(wv * 8);
#pragma unroll 2
        for (int r = 0; r < 8; ++r) {
            const float bx = fmaf(-cB, rowf, P.z);   // per-row partials
            const float by = fmaf( cA, rowf, P.w);
            float* orow = outp + (wv * 8 + r) * WW;
#pragma unroll
            for (int h = 0; h < 2; ++h) {
                const float xf  = xf0 + 64.0f * h;
                const float ix  = fmaf(cA, xf, bx);
                const float iy  = fmaf(cB, xf, by);
                const float xc  = fminf(fmaxf(ix, 0.0f), 129.99f);
                const float yc  = fminf(fmaxf(iy, 0.0f), 129.99f);
                const float x0f = floorf(xc), y0f = floorf(yc);
                const float fx  = xc - x0f,   fy  = yc - y0f;
                const int   a   = (int)y0f * PSTRIDE + (int)x0f;
                const float v00 = lds[a],           v01 = lds[a + 1];           // ds_read2
                const float v10 = lds[a + PSTRIDE], v11 = lds[a + PSTRIDE + 1]; // ds_read2
                const float h0  = fmaf(fx, v01 - v00, v00);
                const float h1  = fmaf(fx, v11 - v10, v10);
                orow[h * 64 + l] = fmaf(fy, h1 - h0, h0);
            }
            rowf += 1.0f;
        }
    }
}

// ---------------------------------------------------------------------------
extern "C" void kernel_launch(void* const* d_in, const int* in_sizes, int n_in,
                              void* d_out, int out_size, void* d_ws, size_t ws_size,
                              hipStream_t stream) {
    const float* feature_map = (const float*)d_in[0];  // [4,256,128,128]
    const float* para_code   = (const float*)d_in[1];  // [4,256]
    const float* W1 = (const float*)d_in[2];
    const float* b1 = (const float*)d_in[3];
    const float* Ws = (const float*)d_in[4];
    const float* bs = (const float*)d_in[5];
    const float* Wr = (const float*)d_in[6];
    const float* br = (const float*)d_in[7];
    const float* Wt = (const float*)d_in[8];
    const float* bt = (const float*)d_in[9];

    float* ws = (float*)d_ws;   // 5120 floats = 20 KiB

    adaat_params_kernel<<<4 * BATCH, 1024, 0, stream>>>(
        para_code, W1, b1, Ws, Wr, Wt, ws);
    adaat_fused_kernel<<<BATCH * CH, 1024, 0, stream>>>(
        feature_map, ws, bs, br, bt, (float*)d_out);
}